// Round 12
// baseline (575.466 us; speedup 1.0000x reference)
//
#include <hip/hip_runtime.h>

// ModernNCA round 12: dist reverted to R9/R10 exact (inline addressing -
// R11's hoisted pointers regressed 255->288us); keep R11's XCD-grouped
// enc_gemm (verified ~43us win).

#define TWO_PI 6.283185307179586f
#define N_CAND 100000
#define N_CPAD 100224           // divisible by 128 and 64
#define N_CB   (N_CPAD / 64)    // 1566 c-bands
#define N_Q    1024
#define KENC   832              // 776 padded to 13*64

typedef unsigned short ushort_t;
typedef unsigned int uint_t;
typedef __attribute__((ext_vector_type(8))) short short8;   // 8 bf16
typedef __attribute__((ext_vector_type(4))) float f32x4;

__device__ __forceinline__ float bf2f(ushort_t h) {
    union { uint_t u; float f; } c; c.u = ((uint_t)h) << 16; return c.f;
}
__device__ __forceinline__ ushort_t f2bf(float f) {
    union { float f; uint_t u; } c; c.f = f;
    uint_t u = c.u + 0x7fffu + ((c.u >> 16) & 1u);   // RNE; inputs finite
    return (ushort_t)(u >> 16);
}

// async global->LDS, 16B per lane; lds dest = wave-uniform base + lane*16
__device__ __forceinline__ void glds16(const void* g, void* l) {
    __builtin_amdgcn_global_load_lds(
        (const __attribute__((address_space(1))) void*)g,
        (__attribute__((address_space(3))) void*)l, 16, 0, 0);
}

// ---------------------------------------------------------------------------
// Prepass: encw[512][776] fp32 -> w_hi bf16 [512][832] (zero pad tail).
// ---------------------------------------------------------------------------
__global__ __launch_bounds__(256) void wsplit_kernel(
    const float* __restrict__ encw, ushort_t* __restrict__ w_hi)
{
    int idx = blockIdx.x * 256 + threadIdx.x;
    if (idx >= 512 * KENC) return;
    int n = idx / KENC, k = idx - n * KENC;
    float w = (k < 776) ? encw[n * 776 + k] : 0.f;
    w_hi[idx] = f2bf(w);
}

// ---------------------------------------------------------------------------
// Counting sort of candidates by class (order within class irrelevant).
// ---------------------------------------------------------------------------
__global__ __launch_bounds__(256) void hist_kernel(
    const int* __restrict__ cy, int* __restrict__ hist,
    int* __restrict__ perm, int* __restrict__ scls)
{
    __shared__ int lh[10];
    int t = threadIdx.x;
    long j = (long)blockIdx.x * 256 + t;
    if (t < 10) lh[t] = 0;
    __syncthreads();
    if (j < N_CAND) atomicAdd(&lh[cy[j]], 1);
    __syncthreads();
    if (t < 10 && lh[t] > 0) atomicAdd(&hist[t], lh[t]);
    if (blockIdx.x == 0 && t < N_CPAD - N_CAND) {   // 224 pad positions
        perm[N_CAND + t] = 0;
        scls[N_CAND + t] = 0;   // harmless: pad p == 0 in dist
    }
}

__global__ void prefix_kernel(const int* __restrict__ hist, int* __restrict__ cursor)
{
    if (threadIdx.x == 0) {
        int run = 0;
        for (int c = 0; c < 10; ++c) { cursor[c] = run; run += hist[c]; }
    }
}

__global__ __launch_bounds__(256) void scatter_kernel(
    const int* __restrict__ cy, int* __restrict__ cursor,
    int* __restrict__ perm, int* __restrict__ scls)
{
    __shared__ int lh[10], lbase[10];
    int t = threadIdx.x;
    long j = (long)blockIdx.x * 256 + t;
    if (t < 10) lh[t] = 0;
    __syncthreads();
    int cls = -1;
    if (j < N_CAND) { cls = cy[j]; atomicAdd(&lh[cls], 1); }
    __syncthreads();
    if (t < 10 && lh[t] > 0) lbase[t] = atomicAdd(&cursor[t], lh[t]);
    __syncthreads();
    if (j < N_CAND) {
        int pos = atomicAdd(&lbase[cls], 1);
        perm[pos] = (int)j;
        scls[pos] = cls;
    }
}

// ---------------------------------------------------------------------------
// PLR: 32 rows/block -> feat_out[local_row][832] bf16. Optional perm gather.
// ---------------------------------------------------------------------------
__global__ __launch_bounds__(256) void plr_kernel(
    const float* __restrict__ vin,    // [nsrc][32]
    int nsrc, long src_base,
    const int*   __restrict__ perm,   // null -> identity (clamped)
    const float* __restrict__ freq,   // [24][16]
    const float* __restrict__ plrw,   // [32][32]
    const float* __restrict__ plrb,   // [32]
    ushort_t*    __restrict__ feat_out) // slab-local [rows][832]
{
    __shared__ float s_cx[32 * 32];
    __shared__ float s_freq[24 * 16];
    __shared__ __align__(16) ushort_t s_feat[32 * KENC];  // 53248 B

    const int t = threadIdx.x;
    const long lbase = (long)blockIdx.x * 32;
    const long gbase = src_base + lbase;
    const int lane = t & 63, w = t >> 6;
    const int lr = lane & 15, g = lane >> 4;

    {
        long idx = gbase + (t >> 3);
        long row;
        if (perm) row = perm[idx];                       // idx < N_CPAD
        else      row = (idx > (long)nsrc - 1) ? nsrc - 1 : idx;
        ((float4*)s_cx)[t] = ((const float4*)(vin + row * 32))[t & 7];
    }
    if (t < 96) {
        float4 f = ((const float4*)freq)[t];
        f.x *= TWO_PI; f.y *= TWO_PI; f.z *= TWO_PI; f.w *= TWO_PI;
        ((float4*)s_freq)[t] = f;
    }
    for (int i = t; i < 896; i += 256) {                 // zero K-tail [776,832)
        int row = i / 28, o = (i - row * 28) * 2;
        *(uint_t*)&s_feat[row * KENC + 776 + o] = 0u;
    }

    short8 pbh[2], pbl[2];
    float pbias[2];
    #pragma unroll
    for (int n = 0; n < 2; ++n) {
        int e = n * 16 + lr;
        const float* pr = plrw + e * 32 + g * 8;
        float wv[8];
        *(float4*)&wv[0] = *(const float4*)pr;
        *(float4*)&wv[4] = *(const float4*)(pr + 4);
        #pragma unroll
        for (int j = 0; j < 8; ++j) {
            ushort_t h = f2bf(wv[j]);
            pbh[n][j] = (short)h;
            pbl[n][j] = (short)f2bf(wv[j] - bf2f(h));
        }
        pbias[n] = plrb[e];
    }
    __syncthreads();

    const bool use_sin = (lane >= 32);
    const int f0 = (g & 1) * 8;
    for (int i = 0; i < 12; ++i) {
        const int tile = w * 12 + i;
        const int m_a = tile * 16 + lr;
        const int rowa = m_a / 24, na = m_a - rowa * 24;
        const float v = s_cx[rowa * 32 + na];
        float ang[8];
        *(float4*)&ang[0] = *(const float4*)&s_freq[na * 16 + f0];
        *(float4*)&ang[4] = *(const float4*)&s_freq[na * 16 + f0 + 4];
        short8 af;
        #pragma unroll
        for (int j = 0; j < 8; ++j) {
            float sv, cv;
            __sincosf(ang[j] * v, &sv, &cv);
            af[j] = (short)f2bf(use_sin ? sv : cv);
        }
        f32x4 c0 = {0.f, 0.f, 0.f, 0.f}, c1 = {0.f, 0.f, 0.f, 0.f};
        c0 = __builtin_amdgcn_mfma_f32_16x16x32_bf16(af, pbh[0], c0, 0, 0, 0);
        c0 = __builtin_amdgcn_mfma_f32_16x16x32_bf16(af, pbl[0], c0, 0, 0, 0);
        c1 = __builtin_amdgcn_mfma_f32_16x16x32_bf16(af, pbh[1], c1, 0, 0, 0);
        c1 = __builtin_amdgcn_mfma_f32_16x16x32_bf16(af, pbl[1], c1, 0, 0, 0);
        #pragma unroll
        for (int r = 0; r < 4; ++r) {
            const int m_c = tile * 16 + g * 4 + r;
            const int rowc = m_c / 24, nc = m_c - rowc * 24;
            s_feat[rowc * KENC + nc * 32 + lr]      = f2bf(fmaxf(c0[r] + pbias[0], 0.f));
            s_feat[rowc * KENC + nc * 32 + 16 + lr] = f2bf(fmaxf(c1[r] + pbias[1], 0.f));
        }
    }
    {
        int c = t >> 3, j = t & 7;
        s_feat[c * KENC + 768 + j] = f2bf(s_cx[c * 32 + 24 + j]);
    }
    __syncthreads();

    uint4* dst = (uint4*)(feat_out + lbase * KENC);
    const uint4* src = (const uint4*)s_feat;
    #pragma unroll
    for (int i = 0; i < 13; ++i)
        dst[t + 256 * i] = src[t + 256 * i];
}

// ---------------------------------------------------------------------------
// Encoder GEMM (R11, verified): 128x128 tile, BK=64, glds staging, W bf16.
// 1-D XCD-grouped grid: rb = (id>>5)*8 + (id&7), nb = (id>>3)&3.
// ---------------------------------------------------------------------------
__global__ __launch_bounds__(256) void enc_gemm_kernel(
    const ushort_t* __restrict__ feat,   // slab-local [rows][832]
    int nrb,                             // row-blocks in this slab
    long mbase,
    const ushort_t* __restrict__ w_hi,
    const float* __restrict__ encb,
    ushort_t* __restrict__ enc_out,      // [.][512]
    float*    __restrict__ sq_out)       // [.]
{
    __shared__ __align__(16) ushort_t s_A[128 * 64];    // 16384 B
    __shared__ __align__(16) ushort_t s_B[128 * 64];    // 16384 B
    __shared__ float s_sq[128];

    const int id = blockIdx.x;
    const int rb = (id >> 5) * 8 + (id & 7);
    if (rb >= nrb) return;
    const int nbase = ((id >> 3) & 3) * 128;
    const long mloc = (long)rb * 128;

    const int t = threadIdx.x;
    const int lane = t & 63, w = t >> 6;
    const int lr = lane & 15, g = lane >> 4;
    const int mrow = (w & 1) * 64, ncol = (w >> 1) * 64;
    const int wu = t & ~63;

    if (t < 128) s_sq[t] = 0.f;

    // hoisted staging bases (k-invariant)
    const ushort_t* fsrc[4];
    const ushort_t* wsrc[4];
    char* ldsA[4]; char* ldsB[4];
    #pragma unroll
    for (int s = 0; s < 4; ++s) {
        int idx = t + 256 * s;
        int row = idx >> 3, seg = (idx & 7) * 8;
        fsrc[s] = &feat[(mloc + row) * KENC + seg];
        wsrc[s] = &w_hi[(size_t)(nbase + row) * KENC + seg];
        ldsA[s] = (char*)s_A + (size_t)(wu + 256 * s) * 16;
        ldsB[s] = (char*)s_B + (size_t)(wu + 256 * s) * 16;
    }

    f32x4 zero4 = {0.f, 0.f, 0.f, 0.f};
    f32x4 acc[4][4];
    #pragma unroll
    for (int mt = 0; mt < 4; ++mt)
        #pragma unroll
        for (int nt = 0; nt < 4; ++nt) acc[mt][nt] = zero4;

    for (int kc = 0; kc < 13; ++kc) {
        const int k0 = kc * 64;
        __syncthreads();
        #pragma unroll
        for (int s = 0; s < 4; ++s) {
            glds16(fsrc[s] + k0, ldsA[s]);
            glds16(wsrc[s] + k0, ldsB[s]);
        }
        __syncthreads();
        #pragma unroll
        for (int kk = 0; kk < 2; ++kk) {
            const int ko = kk * 32 + g * 8;
            short8 a[4], b[4];
            #pragma unroll
            for (int mt = 0; mt < 4; ++mt)
                a[mt] = *(const short8*)&s_A[(mrow + mt * 16 + lr) * 64 + ko];
            #pragma unroll
            for (int nt = 0; nt < 4; ++nt)
                b[nt] = *(const short8*)&s_B[(ncol + nt * 16 + lr) * 64 + ko];
            #pragma unroll
            for (int mt = 0; mt < 4; ++mt)
                #pragma unroll
                for (int nt = 0; nt < 4; ++nt)
                    acc[mt][nt] = __builtin_amdgcn_mfma_f32_16x16x32_bf16(
                        a[mt], b[nt], acc[mt][nt], 0, 0, 0);
        }
    }

    float bias[4];
    #pragma unroll
    for (int nt = 0; nt < 4; ++nt) bias[nt] = encb[nbase + ncol + nt * 16 + lr];

    #pragma unroll
    for (int mt = 0; mt < 4; ++mt) {
        float sqr[4] = {0.f, 0.f, 0.f, 0.f};
        #pragma unroll
        for (int nt = 0; nt < 4; ++nt) {
            #pragma unroll
            for (int r = 0; r < 4; ++r) {
                float v = acc[mt][nt][r] + bias[nt];
                ushort_t hb = f2bf(v);
                float vb = bf2f(hb);
                sqr[r] += vb * vb;
                enc_out[(mbase + mloc + mrow + mt * 16 + g * 4 + r) * 512
                        + nbase + ncol + nt * 16 + lr] = hb;
            }
        }
        #pragma unroll
        for (int r = 0; r < 4; ++r) {
            float vs = sqr[r];
            vs += __shfl_xor(vs, 1);
            vs += __shfl_xor(vs, 2);
            vs += __shfl_xor(vs, 4);
            vs += __shfl_xor(vs, 8);
            if (lr == 0) atomicAdd(&s_sq[mrow + mt * 16 + g * 4 + r], vs);
        }
    }
    __syncthreads();
    if (t < 128) atomicAdd(&sq_out[mbase + mloc + t], s_sq[t]);
}

// ---------------------------------------------------------------------------
// Distance + binning (R9/R10 exact, verified 255us): block 256q x 64c, BK=128,
// swizzled s_ce, XCD-co-scheduled 1-D grid, launch_bounds(256,3),
// inline (recomputed) addressing - hoisting regressed (R11).
// ---------------------------------------------------------------------------
__global__ __launch_bounds__(256, 3) void dist_kernel(
    const ushort_t* __restrict__ xe,   // [1024][512]
    const ushort_t* __restrict__ ce,   // [100224][512] sorted (pad junk)
    const float*    __restrict__ xsq,  // [1024]
    const float*    __restrict__ csq,  // [100224] sorted
    const int*      __restrict__ scls, // [100224] sorted classes (ascending)
    float*          __restrict__ gbins)// [1024][10]
{
    __shared__ __align__(16) ushort_t s_ce[64 * 128];   // 16384 B, XOR-swizzled
    __shared__ float s_csq[64];
    __shared__ int   s_y[64];

    const int id = blockIdx.x;
    const int cband = (id >> 5) * 8 + (id & 7);
    if (cband >= N_CB) return;
    const int qbase = ((id >> 3) & 3) * 256;
    const long cbase = (long)cband * 64;

    const int t = threadIdx.x;
    const int lane = t & 63, w = t >> 6;
    const int lr = lane & 15, g = lane >> 4;
    const int wu = t & ~63;

    if (t < 64) {
        long jc = cbase + t;
        s_y[t]   = scls[jc];
        s_csq[t] = (jc < N_CAND) ? csq[jc] : 1e30f;   // pad: exp -> 0
    }

    f32x4 zero4 = {0.f, 0.f, 0.f, 0.f};
    f32x4 acc[4][4];
    #pragma unroll
    for (int mt = 0; mt < 4; ++mt)
        #pragma unroll
        for (int nt = 0; nt < 4; ++nt) acc[mt][nt] = zero4;

    for (int kc = 0; kc < 4; ++kc) {
        const int k0 = kc * 128;
        __syncthreads();                  // prev chunk consumed (covers init too)
        #pragma unroll
        for (int s = 0; s < 4; ++s) {     // stage ce 64x128, XOR-swizzled source
            int idx = t + 256 * s;
            int row = idx >> 4, pos = idx & 15;
            int seg = pos ^ (row & 15);   // slot pos holds global segment seg
            glds16(&ce[(cbase + row) * 512 + k0 + seg * 8],
                   (char*)s_ce + (size_t)(wu + 256 * s) * 16);
        }
        // xe A-frags: batched direct global (L2-hot), drained by the barrier
        short8 a[4][4];
        #pragma unroll
        for (int kk = 0; kk < 4; ++kk)
            #pragma unroll
            for (int mt = 0; mt < 4; ++mt)
                a[kk][mt] = *(const short8*)
                    &xe[(size_t)(qbase + w * 64 + mt * 16 + lr) * 512 + k0 + kk * 32 + g * 8];
        __syncthreads();                  // drains glds + a-loads
        #pragma unroll
        for (int kk = 0; kk < 4; ++kk) {
            short8 b[4];
            #pragma unroll
            for (int nt = 0; nt < 4; ++nt) {
                int pos = (kk * 4 + g) ^ lr;   // un-swizzle at read: 2-way max
                b[nt] = *(const short8*)&s_ce[(nt * 16 + lr) * 128 + pos * 8];
            }
            #pragma unroll
            for (int mt = 0; mt < 4; ++mt)
                #pragma unroll
                for (int nt = 0; nt < 4; ++nt)
                    acc[mt][nt] = __builtin_amdgcn_mfma_f32_16x16x32_bf16(
                        a[kk][mt], b[nt], acc[mt][nt], 0, 0, 0);
        }
    }

    // epilogue: p = exp(-sqrt(max(|x|^2+|c|^2-2dot, eps)))
    float xq[4][4];
    #pragma unroll
    for (int mt = 0; mt < 4; ++mt)
        #pragma unroll
        for (int r = 0; r < 4; ++r)
            xq[mt][r] = xsq[qbase + w * 64 + mt * 16 + g * 4 + r];

    float cq[4]; int ycls[4];
    #pragma unroll
    for (int nt = 0; nt < 4; ++nt) {
        cq[nt]   = s_csq[nt * 16 + lr];
        ycls[nt] = s_y[nt * 16 + lr];
    }
    #pragma unroll
    for (int mt = 0; mt < 4; ++mt)
        #pragma unroll
        for (int nt = 0; nt < 4; ++nt)
            #pragma unroll
            for (int r = 0; r < 4; ++r) {
                float sqv = xq[mt][r] + cq[nt] - 2.f * acc[mt][nt][r];
                acc[mt][nt][r] = __expf(-sqrtf(fmaxf(sqv, 1e-12f)));
            }

    // class range of this block (sorted => contiguous, usually 1, rarely 2)
    long chi = cbase + 63; if (chi > N_CAND - 1) chi = N_CAND - 1;
    const int cls_lo = s_y[0];
    const int cls_hi = (chi >= cbase) ? s_y[(int)(chi - cbase)] : s_y[0];

    for (int cls = cls_lo; cls <= cls_hi; ++cls) {
        #pragma unroll
        for (int mt = 0; mt < 4; ++mt) {
            #pragma unroll
            for (int r = 0; r < 4; ++r) {
                float s = 0.f;
                #pragma unroll
                for (int nt = 0; nt < 4; ++nt)
                    s += (ycls[nt] == cls) ? acc[mt][nt][r] : 0.f;
                s += __shfl_xor(s, 1);
                s += __shfl_xor(s, 2);
                s += __shfl_xor(s, 4);
                s += __shfl_xor(s, 8);
                if (lr == 0)
                    atomicAdd(&gbins[(size_t)(qbase + w * 64 + mt * 16 + g * 4 + r) * 10 + cls], s);
            }
        }
    }
}

// ---------------------------------------------------------------------------
__global__ __launch_bounds__(256) void final_kernel(
    const float* __restrict__ gbins, float* __restrict__ out)
{
    int q = blockIdx.x * 256 + threadIdx.x;
    if (q >= N_Q) return;
    float b[10], Z = 0.f;
    #pragma unroll
    for (int c = 0; c < 10; ++c) { b[c] = gbins[q * 10 + c]; Z += b[c]; }
    float inv = 1.f / Z;
    #pragma unroll
    for (int c = 0; c < 10; ++c)
        out[q * 10 + c] = logf(b[c] * inv + 1e-7f);
}

// ---------------------------------------------------------------------------
extern "C" void kernel_launch(void* const* d_in, const int* in_sizes, int n_in,
                              void* d_out, int out_size, void* d_ws, size_t ws_size,
                              hipStream_t stream) {
    const float* x  = (const float*)d_in[0];
    const float* cx = (const float*)d_in[1];
    const int*   cy = (const int*)d_in[2];
    const float* fr = (const float*)d_in[3];
    const float* pw = (const float*)d_in[4];
    const float* pb = (const float*)d_in[5];
    const float* ew = (const float*)d_in[6];
    const float* eb = (const float*)d_in[7];
    float* out = (float*)d_out;

    char* ws = (char*)d_ws;
    ushort_t* ce   = (ushort_t*)(ws);                 // 102,629,376 B (100224 rows)
    ushort_t* xe   = (ushort_t*)(ws + 102629376);     //   1,048,576 B
    float*    csq  = (float*)   (ws + 103677952);     //     400,896 B
    float*    xsq  = (float*)   (ws + 104078848);     //       4,096 B
    float*    gbin = (float*)   (ws + 104082944);     //      40,960 B
    int*      hist = (int*)     (ws + 104123904);     //          64 B
    int*      curs = (int*)     (ws + 104123968);     //          64 B
    ushort_t* w_hi = (ushort_t*)(ws + 104124032);     //     851,968 B
    ushort_t* fq   = (ushort_t*)(ws + 105827968);     //   1,703,936 B (gap kept)
    int*      perm = (int*)     (ws + 107531904);     //     400,896 B
    int*      scls = (int*)     (ws + 107932800);     //     400,896 B
    ushort_t* fc   = (ushort_t*)(ws + 108333696);     // slab buffer (rest)

    long avail = (long)ws_size - 108333696L;
    long slab = avail / (KENC * 2);
    slab &= ~127L;
    if (slab > N_CPAD) slab = N_CPAD;
    if (slab < 128)    slab = 128;

    // zero csq + xsq + gbin + hist (contiguous region)
    hipMemsetAsync(csq, 0, 446016, stream);
    wsplit_kernel<<<1664, 256, 0, stream>>>(ew, w_hi);

    // class counting sort
    hist_kernel<<<391, 256, 0, stream>>>(cy, hist, perm, scls);
    prefix_kernel<<<1, 64, 0, stream>>>(hist, curs);
    scatter_kernel<<<391, 256, 0, stream>>>(cy, curs, perm, scls);

    // queries
    plr_kernel<<<N_Q / 32, 256, 0, stream>>>(x, N_Q, 0, nullptr, fr, pw, pb, fq);
    enc_gemm_kernel<<<32, 256, 0, stream>>>(fq, 8, 0, w_hi, eb, xe, xsq);

    // candidates, slab by slab, gathered in sorted order
    for (long sb = 0; sb < N_CPAD; sb += slab) {
        long rows = (N_CPAD - sb < slab) ? (N_CPAD - sb) : slab;
        int nrb = (int)(rows / 128);
        plr_kernel<<<rows / 32, 256, 0, stream>>>(cx, N_CAND, sb, perm, fr, pw, pb, fc);
        enc_gemm_kernel<<<((nrb + 7) / 8) * 32, 256, 0, stream>>>(
            fc, nrb, sb, w_hi, eb, ce, csq);
    }

    // grid: groups of 32 ids = 8 c-bands x 4 q-slabs; pad to full groups
    int ngroups = (N_CB + 7) / 8;
    dist_kernel<<<ngroups * 32, 256, 0, stream>>>(xe, ce, xsq, csq, scls, gbin);
    final_kernel<<<4, 256, 0, stream>>>(gbin, out);
}

// Round 13
// 545.372 us; speedup vs baseline: 1.0552x; 1.0552x over previous
//
#include <hip/hip_runtime.h>

// ModernNCA round 13: enc_gemm gets the R9-verified XOR bank swizzle
// (s_A/s_B reads were 16-way conflicted, same disease dist had pre-R9).
// dist = R9/R12 exact (verified 255us). Everything else unchanged.

#define TWO_PI 6.283185307179586f
#define N_CAND 100000
#define N_CPAD 100224           // divisible by 128 and 64
#define N_CB   (N_CPAD / 64)    // 1566 c-bands
#define N_Q    1024
#define KENC   832              // 776 padded to 13*64

typedef unsigned short ushort_t;
typedef unsigned int uint_t;
typedef __attribute__((ext_vector_type(8))) short short8;   // 8 bf16
typedef __attribute__((ext_vector_type(4))) float f32x4;

__device__ __forceinline__ float bf2f(ushort_t h) {
    union { uint_t u; float f; } c; c.u = ((uint_t)h) << 16; return c.f;
}
__device__ __forceinline__ ushort_t f2bf(float f) {
    union { float f; uint_t u; } c; c.f = f;
    uint_t u = c.u + 0x7fffu + ((c.u >> 16) & 1u);   // RNE; inputs finite
    return (ushort_t)(u >> 16);
}

// async global->LDS, 16B per lane; lds dest = wave-uniform base + lane*16
__device__ __forceinline__ void glds16(const void* g, void* l) {
    __builtin_amdgcn_global_load_lds(
        (const __attribute__((address_space(1))) void*)g,
        (__attribute__((address_space(3))) void*)l, 16, 0, 0);
}

// ---------------------------------------------------------------------------
// Prepass: encw[512][776] fp32 -> w_hi bf16 [512][832] (zero pad tail).
// ---------------------------------------------------------------------------
__global__ __launch_bounds__(256) void wsplit_kernel(
    const float* __restrict__ encw, ushort_t* __restrict__ w_hi)
{
    int idx = blockIdx.x * 256 + threadIdx.x;
    if (idx >= 512 * KENC) return;
    int n = idx / KENC, k = idx - n * KENC;
    float w = (k < 776) ? encw[n * 776 + k] : 0.f;
    w_hi[idx] = f2bf(w);
}

// ---------------------------------------------------------------------------
// Counting sort of candidates by class (order within class irrelevant).
// ---------------------------------------------------------------------------
__global__ __launch_bounds__(256) void hist_kernel(
    const int* __restrict__ cy, int* __restrict__ hist,
    int* __restrict__ perm, int* __restrict__ scls)
{
    __shared__ int lh[10];
    int t = threadIdx.x;
    long j = (long)blockIdx.x * 256 + t;
    if (t < 10) lh[t] = 0;
    __syncthreads();
    if (j < N_CAND) atomicAdd(&lh[cy[j]], 1);
    __syncthreads();
    if (t < 10 && lh[t] > 0) atomicAdd(&hist[t], lh[t]);
    if (blockIdx.x == 0 && t < N_CPAD - N_CAND) {   // 224 pad positions
        perm[N_CAND + t] = 0;
        scls[N_CAND + t] = 0;   // harmless: pad p == 0 in dist
    }
}

__global__ void prefix_kernel(const int* __restrict__ hist, int* __restrict__ cursor)
{
    if (threadIdx.x == 0) {
        int run = 0;
        for (int c = 0; c < 10; ++c) { cursor[c] = run; run += hist[c]; }
    }
}

__global__ __launch_bounds__(256) void scatter_kernel(
    const int* __restrict__ cy, int* __restrict__ cursor,
    int* __restrict__ perm, int* __restrict__ scls)
{
    __shared__ int lh[10], lbase[10];
    int t = threadIdx.x;
    long j = (long)blockIdx.x * 256 + t;
    if (t < 10) lh[t] = 0;
    __syncthreads();
    int cls = -1;
    if (j < N_CAND) { cls = cy[j]; atomicAdd(&lh[cls], 1); }
    __syncthreads();
    if (t < 10 && lh[t] > 0) lbase[t] = atomicAdd(&cursor[t], lh[t]);
    __syncthreads();
    if (j < N_CAND) {
        int pos = atomicAdd(&lbase[cls], 1);
        perm[pos] = (int)j;
        scls[pos] = cls;
    }
}

// ---------------------------------------------------------------------------
// PLR: 32 rows/block -> feat_out[local_row][832] bf16. Optional perm gather.
// ---------------------------------------------------------------------------
__global__ __launch_bounds__(256) void plr_kernel(
    const float* __restrict__ vin,    // [nsrc][32]
    int nsrc, long src_base,
    const int*   __restrict__ perm,   // null -> identity (clamped)
    const float* __restrict__ freq,   // [24][16]
    const float* __restrict__ plrw,   // [32][32]
    const float* __restrict__ plrb,   // [32]
    ushort_t*    __restrict__ feat_out) // slab-local [rows][832]
{
    __shared__ float s_cx[32 * 32];
    __shared__ float s_freq[24 * 16];
    __shared__ __align__(16) ushort_t s_feat[32 * KENC];  // 53248 B

    const int t = threadIdx.x;
    const long lbase = (long)blockIdx.x * 32;
    const long gbase = src_base + lbase;
    const int lane = t & 63, w = t >> 6;
    const int lr = lane & 15, g = lane >> 4;

    {
        long idx = gbase + (t >> 3);
        long row;
        if (perm) row = perm[idx];                       // idx < N_CPAD
        else      row = (idx > (long)nsrc - 1) ? nsrc - 1 : idx;
        ((float4*)s_cx)[t] = ((const float4*)(vin + row * 32))[t & 7];
    }
    if (t < 96) {
        float4 f = ((const float4*)freq)[t];
        f.x *= TWO_PI; f.y *= TWO_PI; f.z *= TWO_PI; f.w *= TWO_PI;
        ((float4*)s_freq)[t] = f;
    }
    for (int i = t; i < 896; i += 256) {                 // zero K-tail [776,832)
        int row = i / 28, o = (i - row * 28) * 2;
        *(uint_t*)&s_feat[row * KENC + 776 + o] = 0u;
    }

    short8 pbh[2], pbl[2];
    float pbias[2];
    #pragma unroll
    for (int n = 0; n < 2; ++n) {
        int e = n * 16 + lr;
        const float* pr = plrw + e * 32 + g * 8;
        float wv[8];
        *(float4*)&wv[0] = *(const float4*)pr;
        *(float4*)&wv[4] = *(const float4*)(pr + 4);
        #pragma unroll
        for (int j = 0; j < 8; ++j) {
            ushort_t h = f2bf(wv[j]);
            pbh[n][j] = (short)h;
            pbl[n][j] = (short)f2bf(wv[j] - bf2f(h));
        }
        pbias[n] = plrb[e];
    }
    __syncthreads();

    const bool use_sin = (lane >= 32);
    const int f0 = (g & 1) * 8;
    for (int i = 0; i < 12; ++i) {
        const int tile = w * 12 + i;
        const int m_a = tile * 16 + lr;
        const int rowa = m_a / 24, na = m_a - rowa * 24;
        const float v = s_cx[rowa * 32 + na];
        float ang[8];
        *(float4*)&ang[0] = *(const float4*)&s_freq[na * 16 + f0];
        *(float4*)&ang[4] = *(const float4*)&s_freq[na * 16 + f0 + 4];
        short8 af;
        #pragma unroll
        for (int j = 0; j < 8; ++j) {
            float sv, cv;
            __sincosf(ang[j] * v, &sv, &cv);
            af[j] = (short)f2bf(use_sin ? sv : cv);
        }
        f32x4 c0 = {0.f, 0.f, 0.f, 0.f}, c1 = {0.f, 0.f, 0.f, 0.f};
        c0 = __builtin_amdgcn_mfma_f32_16x16x32_bf16(af, pbh[0], c0, 0, 0, 0);
        c0 = __builtin_amdgcn_mfma_f32_16x16x32_bf16(af, pbl[0], c0, 0, 0, 0);
        c1 = __builtin_amdgcn_mfma_f32_16x16x32_bf16(af, pbh[1], c1, 0, 0, 0);
        c1 = __builtin_amdgcn_mfma_f32_16x16x32_bf16(af, pbl[1], c1, 0, 0, 0);
        #pragma unroll
        for (int r = 0; r < 4; ++r) {
            const int m_c = tile * 16 + g * 4 + r;
            const int rowc = m_c / 24, nc = m_c - rowc * 24;
            s_feat[rowc * KENC + nc * 32 + lr]      = f2bf(fmaxf(c0[r] + pbias[0], 0.f));
            s_feat[rowc * KENC + nc * 32 + 16 + lr] = f2bf(fmaxf(c1[r] + pbias[1], 0.f));
        }
    }
    {
        int c = t >> 3, j = t & 7;
        s_feat[c * KENC + 768 + j] = f2bf(s_cx[c * 32 + 24 + j]);
    }
    __syncthreads();

    uint4* dst = (uint4*)(feat_out + lbase * KENC);
    const uint4* src = (const uint4*)s_feat;
    #pragma unroll
    for (int i = 0; i < 13; ++i)
        dst[t + 256 * i] = src[t + 256 * i];
}

// ---------------------------------------------------------------------------
// Encoder GEMM (R11 structure + R13 XOR bank swizzle on s_A/s_B):
// 128x128 tile, BK=64, glds staging, W bf16, XCD-grouped 1-D grid.
// Swizzle: LDS slot (row, pos) holds global segment pos^(row&7); quarter-wave
// reads then spread 8 bank-groups (2-way = free) instead of 16-way.
// ---------------------------------------------------------------------------
__global__ __launch_bounds__(256) void enc_gemm_kernel(
    const ushort_t* __restrict__ feat,   // slab-local [rows][832]
    int nrb,                             // row-blocks in this slab
    long mbase,
    const ushort_t* __restrict__ w_hi,
    const float* __restrict__ encb,
    ushort_t* __restrict__ enc_out,      // [.][512]
    float*    __restrict__ sq_out)       // [.]
{
    __shared__ __align__(16) ushort_t s_A[128 * 64];    // 16384 B
    __shared__ __align__(16) ushort_t s_B[128 * 64];    // 16384 B
    __shared__ float s_sq[128];

    const int id = blockIdx.x;
    const int rb = (id >> 5) * 8 + (id & 7);
    if (rb >= nrb) return;
    const int nbase = ((id >> 3) & 3) * 128;
    const long mloc = (long)rb * 128;

    const int t = threadIdx.x;
    const int lane = t & 63, w = t >> 6;
    const int lr = lane & 15, g = lane >> 4;
    const int mrow = (w & 1) * 64, ncol = (w >> 1) * 64;
    const int wu = t & ~63;
    const int xr = lr & 7;                // read-side swizzle key

    if (t < 128) s_sq[t] = 0.f;

    // hoisted staging bases (k-invariant), XOR-swizzled source segments
    const ushort_t* fsrc[4];
    const ushort_t* wsrc[4];
    char* ldsA[4]; char* ldsB[4];
    #pragma unroll
    for (int s = 0; s < 4; ++s) {
        int idx = t + 256 * s;
        int row = idx >> 3;
        int seg = ((idx & 7) ^ (row & 7)) * 8;   // slot idx&7 holds segment seg/8
        fsrc[s] = &feat[(mloc + row) * KENC + seg];
        wsrc[s] = &w_hi[(size_t)(nbase + row) * KENC + seg];
        ldsA[s] = (char*)s_A + (size_t)(wu + 256 * s) * 16;
        ldsB[s] = (char*)s_B + (size_t)(wu + 256 * s) * 16;
    }

    f32x4 zero4 = {0.f, 0.f, 0.f, 0.f};
    f32x4 acc[4][4];
    #pragma unroll
    for (int mt = 0; mt < 4; ++mt)
        #pragma unroll
        for (int nt = 0; nt < 4; ++nt) acc[mt][nt] = zero4;

    for (int kc = 0; kc < 13; ++kc) {
        const int k0 = kc * 64;
        __syncthreads();
        #pragma unroll
        for (int s = 0; s < 4; ++s) {
            glds16(fsrc[s] + k0, ldsA[s]);
            glds16(wsrc[s] + k0, ldsB[s]);
        }
        __syncthreads();
        #pragma unroll
        for (int kk = 0; kk < 2; ++kk) {
            const int pos = ((kk * 4 + g) ^ xr) * 8;   // un-swizzled slot
            short8 a[4], b[4];
            #pragma unroll
            for (int mt = 0; mt < 4; ++mt)
                a[mt] = *(const short8*)&s_A[(mrow + mt * 16 + lr) * 64 + pos];
            #pragma unroll
            for (int nt = 0; nt < 4; ++nt)
                b[nt] = *(const short8*)&s_B[(ncol + nt * 16 + lr) * 64 + pos];
            #pragma unroll
            for (int mt = 0; mt < 4; ++mt)
                #pragma unroll
                for (int nt = 0; nt < 4; ++nt)
                    acc[mt][nt] = __builtin_amdgcn_mfma_f32_16x16x32_bf16(
                        a[mt], b[nt], acc[mt][nt], 0, 0, 0);
        }
    }

    float bias[4];
    #pragma unroll
    for (int nt = 0; nt < 4; ++nt) bias[nt] = encb[nbase + ncol + nt * 16 + lr];

    #pragma unroll
    for (int mt = 0; mt < 4; ++mt) {
        float sqr[4] = {0.f, 0.f, 0.f, 0.f};
        #pragma unroll
        for (int nt = 0; nt < 4; ++nt) {
            #pragma unroll
            for (int r = 0; r < 4; ++r) {
                float v = acc[mt][nt][r] + bias[nt];
                ushort_t hb = f2bf(v);
                float vb = bf2f(hb);
                sqr[r] += vb * vb;
                enc_out[(mbase + mloc + mrow + mt * 16 + g * 4 + r) * 512
                        + nbase + ncol + nt * 16 + lr] = hb;
            }
        }
        #pragma unroll
        for (int r = 0; r < 4; ++r) {
            float vs = sqr[r];
            vs += __shfl_xor(vs, 1);
            vs += __shfl_xor(vs, 2);
            vs += __shfl_xor(vs, 4);
            vs += __shfl_xor(vs, 8);
            if (lr == 0) atomicAdd(&s_sq[mrow + mt * 16 + g * 4 + r], vs);
        }
    }
    __syncthreads();
    if (t < 128) atomicAdd(&sq_out[mbase + mloc + t], s_sq[t]);
}

// ---------------------------------------------------------------------------
// Distance + binning (R9/R12 exact, verified 255us): block 256q x 64c, BK=128,
// swizzled s_ce, XCD-co-scheduled 1-D grid, launch_bounds(256,3),
// inline (recomputed) addressing.
// ---------------------------------------------------------------------------
__global__ __launch_bounds__(256, 3) void dist_kernel(
    const ushort_t* __restrict__ xe,   // [1024][512]
    const ushort_t* __restrict__ ce,   // [100224][512] sorted (pad junk)
    const float*    __restrict__ xsq,  // [1024]
    const float*    __restrict__ csq,  // [100224] sorted
    const int*      __restrict__ scls, // [100224] sorted classes (ascending)
    float*          __restrict__ gbins)// [1024][10]
{
    __shared__ __align__(16) ushort_t s_ce[64 * 128];   // 16384 B, XOR-swizzled
    __shared__ float s_csq[64];
    __shared__ int   s_y[64];

    const int id = blockIdx.x;
    const int cband = (id >> 5) * 8 + (id & 7);
    if (cband >= N_CB) return;
    const int qbase = ((id >> 3) & 3) * 256;
    const long cbase = (long)cband * 64;

    const int t = threadIdx.x;
    const int lane = t & 63, w = t >> 6;
    const int lr = lane & 15, g = lane >> 4;
    const int wu = t & ~63;

    if (t < 64) {
        long jc = cbase + t;
        s_y[t]   = scls[jc];
        s_csq[t] = (jc < N_CAND) ? csq[jc] : 1e30f;   // pad: exp -> 0
    }

    f32x4 zero4 = {0.f, 0.f, 0.f, 0.f};
    f32x4 acc[4][4];
    #pragma unroll
    for (int mt = 0; mt < 4; ++mt)
        #pragma unroll
        for (int nt = 0; nt < 4; ++nt) acc[mt][nt] = zero4;

    for (int kc = 0; kc < 4; ++kc) {
        const int k0 = kc * 128;
        __syncthreads();                  // prev chunk consumed (covers init too)
        #pragma unroll
        for (int s = 0; s < 4; ++s) {     // stage ce 64x128, XOR-swizzled source
            int idx = t + 256 * s;
            int row = idx >> 4, pos = idx & 15;
            int seg = pos ^ (row & 15);   // slot pos holds global segment seg
            glds16(&ce[(cbase + row) * 512 + k0 + seg * 8],
                   (char*)s_ce + (size_t)(wu + 256 * s) * 16);
        }
        // xe A-frags: batched direct global (L2-hot), drained by the barrier
        short8 a[4][4];
        #pragma unroll
        for (int kk = 0; kk < 4; ++kk)
            #pragma unroll
            for (int mt = 0; mt < 4; ++mt)
                a[kk][mt] = *(const short8*)
                    &xe[(size_t)(qbase + w * 64 + mt * 16 + lr) * 512 + k0 + kk * 32 + g * 8];
        __syncthreads();                  // drains glds + a-loads
        #pragma unroll
        for (int kk = 0; kk < 4; ++kk) {
            short8 b[4];
            #pragma unroll
            for (int nt = 0; nt < 4; ++nt) {
                int pos = (kk * 4 + g) ^ lr;   // un-swizzle at read: 2-way max
                b[nt] = *(const short8*)&s_ce[(nt * 16 + lr) * 128 + pos * 8];
            }
            #pragma unroll
            for (int mt = 0; mt < 4; ++mt)
                #pragma unroll
                for (int nt = 0; nt < 4; ++nt)
                    acc[mt][nt] = __builtin_amdgcn_mfma_f32_16x16x32_bf16(
                        a[kk][mt], b[nt], acc[mt][nt], 0, 0, 0);
        }
    }

    // epilogue: p = exp(-sqrt(max(|x|^2+|c|^2-2dot, eps)))
    float xq[4][4];
    #pragma unroll
    for (int mt = 0; mt < 4; ++mt)
        #pragma unroll
        for (int r = 0; r < 4; ++r)
            xq[mt][r] = xsq[qbase + w * 64 + mt * 16 + g * 4 + r];

    float cq[4]; int ycls[4];
    #pragma unroll
    for (int nt = 0; nt < 4; ++nt) {
        cq[nt]   = s_csq[nt * 16 + lr];
        ycls[nt] = s_y[nt * 16 + lr];
    }
    #pragma unroll
    for (int mt = 0; mt < 4; ++mt)
        #pragma unroll
        for (int nt = 0; nt < 4; ++nt)
            #pragma unroll
            for (int r = 0; r < 4; ++r) {
                float sqv = xq[mt][r] + cq[nt] - 2.f * acc[mt][nt][r];
                acc[mt][nt][r] = __expf(-sqrtf(fmaxf(sqv, 1e-12f)));
            }

    // class range of this block (sorted => contiguous, usually 1, rarely 2)
    long chi = cbase + 63; if (chi > N_CAND - 1) chi = N_CAND - 1;
    const int cls_lo = s_y[0];
    const int cls_hi = (chi >= cbase) ? s_y[(int)(chi - cbase)] : s_y[0];

    for (int cls = cls_lo; cls <= cls_hi; ++cls) {
        #pragma unroll
        for (int mt = 0; mt < 4; ++mt) {
            #pragma unroll
            for (int r = 0; r < 4; ++r) {
                float s = 0.f;
                #pragma unroll
                for (int nt = 0; nt < 4; ++nt)
                    s += (ycls[nt] == cls) ? acc[mt][nt][r] : 0.f;
                s += __shfl_xor(s, 1);
                s += __shfl_xor(s, 2);
                s += __shfl_xor(s, 4);
                s += __shfl_xor(s, 8);
                if (lr == 0)
                    atomicAdd(&gbins[(size_t)(qbase + w * 64 + mt * 16 + g * 4 + r) * 10 + cls], s);
            }
        }
    }
}

// ---------------------------------------------------------------------------
__global__ __launch_bounds__(256) void final_kernel(
    const float* __restrict__ gbins, float* __restrict__ out)
{
    int q = blockIdx.x * 256 + threadIdx.x;
    if (q >= N_Q) return;
    float b[10], Z = 0.f;
    #pragma unroll
    for (int c = 0; c < 10; ++c) { b[c] = gbins[q * 10 + c]; Z += b[c]; }
    float inv = 1.f / Z;
    #pragma unroll
    for (int c = 0; c < 10; ++c)
        out[q * 10 + c] = logf(b[c] * inv + 1e-7f);
}

// ---------------------------------------------------------------------------
extern "C" void kernel_launch(void* const* d_in, const int* in_sizes, int n_in,
                              void* d_out, int out_size, void* d_ws, size_t ws_size,
                              hipStream_t stream) {
    const float* x  = (const float*)d_in[0];
    const float* cx = (const float*)d_in[1];
    const int*   cy = (const int*)d_in[2];
    const float* fr = (const float*)d_in[3];
    const float* pw = (const float*)d_in[4];
    const float* pb = (const float*)d_in[5];
    const float* ew = (const float*)d_in[6];
    const float* eb = (const float*)d_in[7];
    float* out = (float*)d_out;

    char* ws = (char*)d_ws;
    ushort_t* ce   = (ushort_t*)(ws);                 // 102,629,376 B (100224 rows)
    ushort_t* xe   = (ushort_t*)(ws + 102629376);     //   1,048,576 B
    float*    csq  = (float*)   (ws + 103677952);     //     400,896 B
    float*    xsq  = (float*)   (ws + 104078848);     //       4,096 B
    float*    gbin = (float*)   (ws + 104082944);     //      40,960 B
    int*      hist = (int*)     (ws + 104123904);     //          64 B
    int*      curs = (int*)     (ws + 104123968);     //          64 B
    ushort_t* w_hi = (ushort_t*)(ws + 104124032);     //     851,968 B
    ushort_t* fq   = (ushort_t*)(ws + 105827968);     //   1,703,936 B (gap kept)
    int*      perm = (int*)     (ws + 107531904);     //     400,896 B
    int*      scls = (int*)     (ws + 107932800);     //     400,896 B
    ushort_t* fc   = (ushort_t*)(ws + 108333696);     // slab buffer (rest)

    long avail = (long)ws_size - 108333696L;
    long slab = avail / (KENC * 2);
    slab &= ~127L;
    if (slab > N_CPAD) slab = N_CPAD;
    if (slab < 128)    slab = 128;

    // zero csq + xsq + gbin + hist (contiguous region)
    hipMemsetAsync(csq, 0, 446016, stream);
    wsplit_kernel<<<1664, 256, 0, stream>>>(ew, w_hi);

    // class counting sort
    hist_kernel<<<391, 256, 0, stream>>>(cy, hist, perm, scls);
    prefix_kernel<<<1, 64, 0, stream>>>(hist, curs);
    scatter_kernel<<<391, 256, 0, stream>>>(cy, curs, perm, scls);

    // queries
    plr_kernel<<<N_Q / 32, 256, 0, stream>>>(x, N_Q, 0, nullptr, fr, pw, pb, fq);
    enc_gemm_kernel<<<32, 256, 0, stream>>>(fq, 8, 0, w_hi, eb, xe, xsq);

    // candidates, slab by slab, gathered in sorted order
    for (long sb = 0; sb < N_CPAD; sb += slab) {
        long rows = (N_CPAD - sb < slab) ? (N_CPAD - sb) : slab;
        int nrb = (int)(rows / 128);
        plr_kernel<<<rows / 32, 256, 0, stream>>>(cx, N_CAND, sb, perm, fr, pw, pb, fc);
        enc_gemm_kernel<<<((nrb + 7) / 8) * 32, 256, 0, stream>>>(
            fc, nrb, sb, w_hi, eb, ce, csq);
    }

    // grid: groups of 32 ids = 8 c-bands x 4 q-slabs; pad to full groups
    int ngroups = (N_CB + 7) / 8;
    dist_kernel<<<ngroups * 32, 256, 0, stream>>>(xe, ce, xsq, csq, scls, gbin);
    final_kernel<<<4, 256, 0, stream>>>(gbin, out);
}